// Round 6
// baseline (2012.031 us; speedup 1.0000x reference)
//
#include <hip/hip_runtime.h>

namespace {
constexpr int T    = 2048;
constexpr int Bsz  = 4096;
constexpr int H    = 51;     // hidden units
constexpr int H4   = 204;    // 4*H gate rows
constexpr int NB   = 8;      // batches per block
constexpr int BLK  = 512;    // 8 waves
constexpr int GRID = Bsz / NB;  // 512 blocks = 2 per CU (independent barrier domains)
constexpr float SCI = -1.44269504f;   // -log2(e), gates i,f,o
constexpr float SCG = -2.88539008f;   // -2*log2(e), gate g
}

typedef float    f32x4 __attribute__((ext_vector_type(4)));
typedef _Float16 f16x8 __attribute__((ext_vector_type(8)));
typedef unsigned short u16;

__device__ __forceinline__ float RCP(float x)  { return __builtin_amdgcn_rcpf(x); }
__device__ __forceinline__ float EXP2(float x) { return __builtin_amdgcn_exp2f(x); }

// Inputs pre-scaled: Gi=-log2e*gi, Gf=-log2e*gf, Gg=-2log2e*gg, Go=-log2e*go
__device__ __forceinline__ float lstm_act(float Gi, float Gf, float Gg, float Go, float& c) {
  float ei = EXP2(Gi);
  float ef = EXP2(Gf);
  float eo = EXP2(Go);
  float eg = EXP2(-fabsf(Gg));
  float pi = 1.0f + ei, pf = 1.0f + ef, pg = 1.0f + eg;
  float tg = copysignf(1.0f - eg, -Gg);
  float pig = pi * pg;
  float num = fmaf(c, pig, tg * pf);
  c = num * RCP(pig * pf);
  float ec = EXP2(SCG * fabsf(c));
  float tc = copysignf(1.0f - ec, c);
  return tc * RCP((1.0f + eo) * (1.0f + ec));
}

// merge tile-pair D fragments: lanes a<8 keep dA, lanes a>=8 take dB from lane-8
// (v_mov_dpp row_shr:8 = 0x118; invalid lanes keep `old`)
__device__ __forceinline__ float dpp_sel(float dA, float dB) {
  return __uint_as_float((unsigned)__builtin_amdgcn_update_dpp(
      (int)__float_as_uint(dA), (int)__float_as_uint(dB), 0x118, 0xf, 0xf, false));
}

// Fragment k-map (validated r2-r5): lane = free(0..15)+16*q ; elem j: k = 32*sp+16*(j>>2)+4*q+(j&3)
// h-plane slot (b,k): sp=k>>5, kl=k&31, row=b+16*((kl>>2)&3), j=(kl&3)+4*(kl>>4)
// PL shorts: [buf(2)][layer(2)][sp(2)][row(64)][j(8)] = 4096 shorts = 8KB (b<8 rows used)
// L1 k-slots: k<51 h1 | 51 x0 | 52 x1 | 53 const1 ; L2 (k-64): <51 h2 | 53 const1

__global__ __launch_bounds__(BLK, 4) void lstm2_v6(
    const float* __restrict__ x,
    const float* __restrict__ Wih1, const float* __restrict__ Whh1,
    const float* __restrict__ bih1, const float* __restrict__ bhh1,
    const float* __restrict__ Wih2, const float* __restrict__ Whh2,
    const float* __restrict__ bih2, const float* __restrict__ bhh2,
    const float* __restrict__ Wlin, const float* __restrict__ blin,
    float* __restrict__ out) {
  __shared__ __align__(16) float  SW[H4 * H];     // 41.6 KB staging (init only)
  __shared__ __align__(16) u16    PL[4096];       // 8 KB h-plane ping-pong
  __shared__ __align__(16) float4 XB4[2][32][4];  // 4 KB x chunk double-buffer
  __shared__ __align__(16) float  OB[2][8][36];   // 2.3 KB out chunk

  const int tid  = threadIdx.x;
  const int lane = tid & 63;
  const int wid  = tid >> 6;
  const int a    = lane & 15;
  const int q    = lane >> 4;
  const int b0   = blockIdx.x * NB;

  // role rotation by block parity: the two co-resident blocks' special waves
  // land on different SIMDs -> every SIMD sees 7 act-tasks + <=1 special
  const int role = (wid + ((blockIdx.x & 1) << 1)) & 7;
  int l1A = -1, l1B = -1, l2A = -1, l2B = -1;
  bool isSpec = false;
  if (role < 6)       { l1A = 2 * role; l1B = l1A + 1; l2A = l1A; l2B = l1B; }
  else if (role == 6) { l1A = 12; }
  else                { l2A = 12; isSpec = true; }   // + head + xinj + chores

  // ---------------- init: weight A-fragments (pre-scaled single fp16) ----------------
  f16x8 wA1[2][2];   // [tile][sp]  L1: Whh1 | Wih1 cols | bias1 (K=64)
  f16x8 wA2[2][4];   // [tile][sp]  L2: sp0-1 Wih2+bias2, sp2-3 Whh2 (K=128)
  f16x8 hA[2];       // head: Wlin+blin (single fp16)

  for (int i = tid; i < H4 * H; i += BLK) SW[i] = Whh1[i];
  __syncthreads();
#pragma unroll
  for (int ti = 0; ti < 2; ++ti) {
    const int t = ti ? l1B : l1A;
    if (t >= 0) {
      const int  rp   = 16 * t + a;
      const bool vld  = (rp < H4);
      const int  gate = rp & 3;
      const int  wrow = gate * H + (rp >> 2);
      const float sc  = (gate == 2) ? SCG : SCI;
#pragma unroll
      for (int sp = 0; sp < 2; ++sp)
#pragma unroll
        for (int j = 0; j < 8; ++j) {
          const int k = 32 * sp + 16 * (j >> 2) + 4 * q + (j & 3);
          float val = 0.f;
          if (vld) {
            if (k < H)           val = SW[wrow * H + k];
            else if (k == H)     val = Wih1[wrow * 2 + 0];
            else if (k == H + 1) val = Wih1[wrow * 2 + 1];
            else if (k == H + 2) val = bih1[wrow] + bhh1[wrow];
          }
          wA1[ti][sp][j] = (_Float16)(val * sc);
        }
    }
  }
  __syncthreads();
  for (int i = tid; i < H4 * H; i += BLK) SW[i] = Wih2[i];
  __syncthreads();
#pragma unroll
  for (int ti = 0; ti < 2; ++ti) {
    const int t = ti ? l2B : l2A;
    if (t >= 0) {
      const int  rp   = 16 * t + a;
      const bool vld  = (rp < H4);
      const int  gate = rp & 3;
      const int  wrow = gate * H + (rp >> 2);
      const float sc  = (gate == 2) ? SCG : SCI;
#pragma unroll
      for (int sp = 0; sp < 2; ++sp)
#pragma unroll
        for (int j = 0; j < 8; ++j) {
          const int k = 32 * sp + 16 * (j >> 2) + 4 * q + (j & 3);
          float val = 0.f;
          if (vld) {
            if (k < H)           val = SW[wrow * H + k];
            else if (k == H + 2) val = bih2[wrow] + bhh2[wrow];
          }
          wA2[ti][sp][j] = (_Float16)(val * sc);
        }
    }
  }
  __syncthreads();
  for (int i = tid; i < H4 * H; i += BLK) SW[i] = Whh2[i];
  __syncthreads();
#pragma unroll
  for (int ti = 0; ti < 2; ++ti) {
    const int t = ti ? l2B : l2A;
    if (t >= 0) {
      const int  rp   = 16 * t + a;
      const bool vld  = (rp < H4);
      const int  gate = rp & 3;
      const int  wrow = gate * H + (rp >> 2);
      const float sc  = (gate == 2) ? SCG : SCI;
#pragma unroll
      for (int sp = 2; sp < 4; ++sp)
#pragma unroll
        for (int j = 0; j < 8; ++j) {
          const int kp = 32 * (sp - 2) + 16 * (j >> 2) + 4 * q + (j & 3);
          float val = (vld && kp < H) ? SW[wrow * H + kp] * sc : 0.f;
          wA2[ti][sp][j] = (_Float16)val;
        }
    }
  }
  if (isSpec) {
#pragma unroll
    for (int sp = 0; sp < 2; ++sp)
#pragma unroll
      for (int j = 0; j < 8; ++j) {
        const int kp = 32 * sp + 16 * (j >> 2) + 4 * q + (j & 3);
        float val = 0.f;
        if (a == 0) {
          if (kp < H)           val = Wlin[kp];
          else if (kp == H + 2) val = blin[0];
        }
        hA[sp][j] = (_Float16)val;
      }
  }

  // ---------------- init planes + x chunk 0 ----------------
  __syncthreads();
  for (int i = tid; i < 4096; i += BLK) PL[i] = 0;
  if (tid < 128) {  // preload x chunk 0 (steps 0..31): 128 float4
    const int st = tid >> 2, v4 = tid & 3;
    XB4[0][st][v4] = *(const float4*)(x + ((size_t)st * Bsz + b0) * 2 + v4 * 4);
  }
  __syncthreads();
  if (tid < 16) {
#pragma unroll
    for (int buf = 0; buf < 2; ++buf) {
      PL[(buf * 4 + 1) * 512 + (tid + 16) * 8 + 5] = 0x3C00;  // L1 const-1 (fp16 1.0)
      PL[(buf * 4 + 3) * 512 + (tid + 16) * 8 + 5] = 0x3C00;  // L2 const-1
    }
  }
  __syncthreads();
  if (isSpec && lane < 16) {  // inject x(0) into plane buf0
    const int bb = lane & 7, f = (lane >> 3) & 1;
    const float xv = ((const float*)&XB4[0][0][0])[bb * 2 + f];
    const int idx = 512 + ((f == 0) ? bb * 8 + 7 : (bb + 16) * 8 + 4);
    *(_Float16*)&PL[idx] = (_Float16)xv;
  }
  __syncthreads();

  // precomputed plane-write slots (lane owns u = 4*tile+q, batch b = a&7)
  int widx1 = 0, widx2 = 0;
  bool uval1 = false, uval2 = false;
  {
    const int tt = (a < 8) ? l1A : l1B;
    if (tt >= 0) {
      const int u = 4 * tt + q;
      if (u < H) {
        uval1 = true;
        const int spl = u >> 5, kl = u & 31;
        widx1 = spl * 512 + ((a & 7) + 16 * ((kl >> 2) & 3)) * 8 + ((kl & 3) + 4 * (kl >> 4));
      }
    }
  }
  {
    const int tt = (a < 8) ? l2A : l2B;
    if (tt >= 0) {
      const int u = 4 * tt + q;
      if (u < H) {
        uval2 = true;
        const int spl = u >> 5, kl = u & 31;
        widx2 = 1024 + spl * 512 + ((a & 7) + 16 * ((kl >> 2) & 3)) * 8 + ((kl & 3) + 4 * (kl >> 4));
      }
    }
  }

  float c1 = 0.f, c2 = 0.f;
  float4 xcr0 = {0.f, 0.f, 0.f, 0.f}, xcr1 = {0.f, 0.f, 0.f, 0.f};

  for (int s = 0; s < T + 3; ++s) {
    const int pb   = (s & 1) * 2048;
    const int nbuf = 2048 - pb;

    // B-fragment reads
    f16x8 bh0, bh1, bh2, bh3;
    if (l1A >= 0 || l2A >= 0) {
      bh0 = *(const f16x8*)&PL[pb + lane * 8];
      bh1 = *(const f16x8*)&PL[pb + 512 + lane * 8];
    }
    if (l2A >= 0) {
      bh2 = *(const f16x8*)&PL[pb + 1024 + lane * 8];
      bh3 = *(const f16x8*)&PL[pb + 1536 + lane * 8];
    }

    // chores (spec wave): x chunk load / XB write / out flush
    if (isSpec) {
      const int ph = s & 31;
      if (ph == 0) {
        if (s + 32 < T) {
          const int st = lane >> 2, v4 = lane & 3;
          xcr0 = *(const float4*)(x + ((size_t)(s + 32 + st) * Bsz + b0) * 2 + v4 * 4);
          xcr1 = *(const float4*)(x + ((size_t)(s + 48 + st) * Bsz + b0) * 2 + v4 * 4);
        }
      } else if (ph == 1) {
        if (s + 31 < T) {
          const int buf = ((s >> 5) + 1) & 1;
          const int st = lane >> 2, v4 = lane & 3;
          XB4[buf][st][v4]      = xcr0;
          XB4[buf][16 + st][v4] = xcr1;
        }
      } else if (ph == 2 && s >= 34) {
        const int f = (s - 34) >> 5;
        const int row = lane >> 3, c4 = (lane & 7) * 4;
        const float4 v = *(const float4*)&OB[f & 1][row][c4];
        *(float4*)(out + (size_t)(b0 + row) * T + f * 32 + c4) = v;
      }
    }

    // MFMA
    f32x4 dA1, dB1, dA2, dB2;
    if (l1A >= 0) {
      f32x4 acc = {0.f, 0.f, 0.f, 0.f};
      acc = __builtin_amdgcn_mfma_f32_16x16x32_f16(wA1[0][0], bh0, acc, 0, 0, 0);
      acc = __builtin_amdgcn_mfma_f32_16x16x32_f16(wA1[0][1], bh1, acc, 0, 0, 0);
      dA1 = acc;
      if (l1B >= 0) {
        f32x4 ac2 = {0.f, 0.f, 0.f, 0.f};
        ac2 = __builtin_amdgcn_mfma_f32_16x16x32_f16(wA1[1][0], bh0, ac2, 0, 0, 0);
        ac2 = __builtin_amdgcn_mfma_f32_16x16x32_f16(wA1[1][1], bh1, ac2, 0, 0, 0);
        dB1 = ac2;
      }
    }
    if (l2A >= 0) {
      f32x4 acc = {0.f, 0.f, 0.f, 0.f};
      acc = __builtin_amdgcn_mfma_f32_16x16x32_f16(wA2[0][0], bh0, acc, 0, 0, 0);
      acc = __builtin_amdgcn_mfma_f32_16x16x32_f16(wA2[0][1], bh1, acc, 0, 0, 0);
      acc = __builtin_amdgcn_mfma_f32_16x16x32_f16(wA2[0][2], bh2, acc, 0, 0, 0);
      acc = __builtin_amdgcn_mfma_f32_16x16x32_f16(wA2[0][3], bh3, acc, 0, 0, 0);
      dA2 = acc;
      if (l2B >= 0) {
        f32x4 ac2 = {0.f, 0.f, 0.f, 0.f};
        ac2 = __builtin_amdgcn_mfma_f32_16x16x32_f16(wA2[1][0], bh0, ac2, 0, 0, 0);
        ac2 = __builtin_amdgcn_mfma_f32_16x16x32_f16(wA2[1][1], bh1, ac2, 0, 0, 0);
        ac2 = __builtin_amdgcn_mfma_f32_16x16x32_f16(wA2[1][2], bh2, ac2, 0, 0, 0);
        ac2 = __builtin_amdgcn_mfma_f32_16x16x32_f16(wA2[1][3], bh3, ac2, 0, 0, 0);
        dB2 = ac2;
      }
    }

    // activations + h-plane writes
    if (l1A >= 0 && s < T) {
      float g0, g1, g2, g3;
      if (l1B >= 0) {
        g0 = dpp_sel(dA1[0], dB1[0]); g1 = dpp_sel(dA1[1], dB1[1]);
        g2 = dpp_sel(dA1[2], dB1[2]); g3 = dpp_sel(dA1[3], dB1[3]);
      } else { g0 = dA1[0]; g1 = dA1[1]; g2 = dA1[2]; g3 = dA1[3]; }
      const float h1 = lstm_act(g0, g1, g2, g3, c1);
      if (uval1) *(_Float16*)&PL[nbuf + widx1] = (_Float16)h1;
    }
    if (l2A >= 0 && s >= 1 && s <= T) {
      float g0, g1, g2, g3;
      if (l2B >= 0) {
        g0 = dpp_sel(dA2[0], dB2[0]); g1 = dpp_sel(dA2[1], dB2[1]);
        g2 = dpp_sel(dA2[2], dB2[2]); g3 = dpp_sel(dA2[3], dB2[3]);
      } else { g0 = dA2[0]; g1 = dA2[1]; g2 = dA2[2]; g3 = dA2[3]; }
      const float h2 = lstm_act(g0, g1, g2, g3, c2);
      if (uval2) *(_Float16*)&PL[nbuf + widx2] = (_Float16)h2;
    }

    // head: out(s-2) -> OB ; x(s+1) injection
    if (isSpec) {
      f32x4 dh = {0.f, 0.f, 0.f, 0.f};
      dh = __builtin_amdgcn_mfma_f32_16x16x32_f16(hA[0], bh2, dh, 0, 0, 0);
      dh = __builtin_amdgcn_mfma_f32_16x16x32_f16(hA[1], bh3, dh, 0, 0, 0);
      if (s >= 2 && s - 2 < T && lane < 8)
        OB[((s - 2) >> 5) & 1][lane][(s - 2) & 31] = dh[0];
      if (lane < 16 && s + 1 < T) {
        const int bb = lane & 7, f = (lane >> 3) & 1;
        const int st = (s + 1) & 31, cb = ((s + 1) >> 5) & 1;
        const float xv = ((const float*)&XB4[cb][st][0])[bb * 2 + f];
        const int idx = nbuf + 512 + ((f == 0) ? bb * 8 + 7 : (bb + 16) * 8 + 4);
        *(_Float16*)&PL[idx] = (_Float16)xv;
      }
    }
    __syncthreads();
  }
}

extern "C" void kernel_launch(void* const* d_in, const int* in_sizes, int n_in,
                              void* d_out, int out_size, void* d_ws, size_t ws_size,
                              hipStream_t stream) {
  (void)in_sizes; (void)n_in; (void)d_ws; (void)ws_size; (void)out_size;
  const float* x    = (const float*)d_in[0];
  const float* Wih1 = (const float*)d_in[1];
  const float* Whh1 = (const float*)d_in[2];
  const float* bih1 = (const float*)d_in[3];
  const float* bhh1 = (const float*)d_in[4];
  const float* Wih2 = (const float*)d_in[5];
  const float* Whh2 = (const float*)d_in[6];
  const float* bih2 = (const float*)d_in[7];
  const float* bhh2 = (const float*)d_in[8];
  const float* Wlin = (const float*)d_in[9];
  const float* blin = (const float*)d_in[10];
  float* out = (float*)d_out;

  hipLaunchKernelGGL(lstm2_v6, dim3(GRID), dim3(BLK), 0, stream,
                     x, Wih1, Whh1, bih1, bhh1, Wih2, Whh2, bih2, bhh2,
                     Wlin, blin, out);
}

// Round 7
// 1587.188 us; speedup vs baseline: 1.2677x; 1.2677x over previous
//
#include <hip/hip_runtime.h>

namespace {
constexpr int T    = 2048;
constexpr int Bsz  = 4096;
constexpr int H    = 51;     // hidden units
constexpr int H4   = 204;    // 4*H gate rows
constexpr int NB   = 16;     // batches per block = MFMA free dim
constexpr int BLK  = 512;    // 8 waves, 2 per SIMD (tile-consolidated)
constexpr int GRID = Bsz / NB;  // 256 blocks = 1/CU
constexpr float SCI  = -1.44269504f;  // -log2(e): i,f,o gates
constexpr float SCGP =  2.88539008f;  // +2*log2(e): g gate (|g|<=~15 -> e^{2g} finite)
constexpr float SC2  = -2.88539008f;  // -2*log2(e): tanh(c), abs-form (c unbounded)
}

typedef float    f32x4 __attribute__((ext_vector_type(4)));
typedef _Float16 f16x8 __attribute__((ext_vector_type(8)));
typedef unsigned short u16;

__device__ __forceinline__ float RCP(float x)  { return __builtin_amdgcn_rcpf(x); }
__device__ __forceinline__ float EXP2(float x) { return __builtin_amdgcn_exp2f(x); }

// Gi=-log2e*i, Gf=-log2e*f, Gg=+2log2e*g, Go=-log2e*o (pre-scaled into weights)
// c' = sigm(f)*c + sigm(i)*tanh(g) = [c*pig + (eg-1)*pf] / (pig*pf)
// h  = sigm(o)*tanh(c') = copysign(1-ec, c') / ((1+ec)*po)
__device__ __forceinline__ float lstm_act(float Gi, float Gf, float Gg, float Go, float& c) {
  float ei = EXP2(Gi), ef = EXP2(Gf), eo = EXP2(Go), eg = EXP2(Gg);
  float pi = 1.f + ei, pf = 1.f + ef, pg = 1.f + eg, po = 1.f + eo;
  float pig = pi * pg;
  float num = fmaf(c, pig, (eg - 1.f) * pf);
  c = num * RCP(pig * pf);
  float ec = EXP2(SC2 * fabsf(c));
  float tc = copysignf(1.f - ec, c);
  return tc * RCP((1.f + ec) * po);
}

// main-loop barrier: LDS-visibility only; do NOT drain vmcnt (chore wave's
// global loads/stores stay in flight across barriers)
#define BAR() asm volatile("s_waitcnt lgkmcnt(0)\n\ts_barrier" ::: "memory")

// Fragment k-map (validated r2-r6): lane = free(0..15)+16*q ; elem j: k = 32*sp+16*(j>>2)+4*q+(j&3)
// h-plane slot (b,k): sp=k>>5, kl=k&31, row=b+16*((kl>>2)&3), j=(kl&3)+4*(kl>>4)
// PL shorts: [buf(2)][layer(2)][sp(2)][row(64)][j(8)] = 4096 shorts = 8KB
// L1 k-slots: k<51 h1 | 51 x0 | 52 x1 | 53 const1 ; L2 (k-64): <51 h2 | 53 const1

__global__ __launch_bounds__(BLK, 1) void lstm2_v7(
    const float* __restrict__ x,
    const float* __restrict__ Wih1, const float* __restrict__ Whh1,
    const float* __restrict__ bih1, const float* __restrict__ bhh1,
    const float* __restrict__ Wih2, const float* __restrict__ Whh2,
    const float* __restrict__ bih2, const float* __restrict__ bhh2,
    const float* __restrict__ Wlin, const float* __restrict__ blin,
    float* __restrict__ out) {
  __shared__ __align__(16) float  SW[H4 * H];      // 41.6 KB staging (init only)
  __shared__ __align__(16) u16    PL[4096];        // 8 KB h-plane ping-pong
  __shared__ __align__(16) float2 XB[2][32][16];   // 8 KB x chunk double-buffer
  __shared__ __align__(16) float  OB[2][16][36];   // 4.6 KB out chunk (36: 16B-aligned rows)

  const int tid  = threadIdx.x;
  const int lane = tid & 63;
  const int wid  = tid >> 6;
  const int a    = lane & 15;
  const int q    = lane >> 4;
  const int b0   = blockIdx.x * NB;

  // tile consolidation: each wave owns up to 2 L1-tiles + 2 L2-tiles and reads
  // the shared B-fragments ONCE (LDS read volume 54KB -> 32KB per slot).
  // SIMD act balance ({w0,w4},{w1,w5},{w2,w6},{w3,w7}): 7 / 7 / 7 / 5+head
  int t1[2] = {-1, -1}, t2[2] = {-1, -1};
  switch (wid) {
    case 0: t1[0]=0;  t1[1]=1;  t2[0]=0;  t2[1]=1;  break;
    case 1: t1[0]=2;  t1[1]=3;  t2[0]=2;  t2[1]=3;  break;
    case 2: t1[0]=4;  t1[1]=5;  t2[0]=4;  t2[1]=5;  break;
    case 3: t1[0]=6;  t1[1]=7;  t2[0]=6;  t2[1]=7;  break;
    case 4: t1[0]=8;  t1[1]=9;  t2[0]=8;            break;
    case 5: t1[0]=10; t1[1]=11; t2[0]=9;            break;
    case 6: t1[0]=12;           t2[0]=10; t2[1]=11; break;
    case 7:                     t2[0]=12;           break;
  }
  const bool isSpec = (wid == 7);   // head + x-inject + chores

  // ---------------- init: weight A-fragments (pre-scaled single fp16) ----------------
  f16x8 wA1[2][2];   // [tile][sp]  L1: Whh1 | Wih1 cols | bias1 (K=64)
  f16x8 wA2[2][4];   // [tile][sp]  L2: sp0-1 Wih2+bias2, sp2-3 Whh2 (K=128)
  f16x8 hA[2];       // head: Wlin+blin

  for (int i = tid; i < H4 * H; i += BLK) SW[i] = Whh1[i];
  __syncthreads();
#pragma unroll
  for (int ti = 0; ti < 2; ++ti) {
    const int t = t1[ti];
    if (t >= 0) {
      const int  rp   = 16 * t + a;
      const bool vld  = (rp < H4);
      const int  gate = rp & 3;
      const int  wrow = gate * H + (rp >> 2);
      const float sc  = (gate == 2) ? SCGP : SCI;
#pragma unroll
      for (int sp = 0; sp < 2; ++sp)
#pragma unroll
        for (int j = 0; j < 8; ++j) {
          const int k = 32 * sp + 16 * (j >> 2) + 4 * q + (j & 3);
          float val = 0.f;
          if (vld) {
            if (k < H)           val = SW[wrow * H + k];
            else if (k == H)     val = Wih1[wrow * 2 + 0];
            else if (k == H + 1) val = Wih1[wrow * 2 + 1];
            else if (k == H + 2) val = bih1[wrow] + bhh1[wrow];
          }
          wA1[ti][sp][j] = (_Float16)(val * sc);
        }
    }
  }
  __syncthreads();
  for (int i = tid; i < H4 * H; i += BLK) SW[i] = Wih2[i];
  __syncthreads();
#pragma unroll
  for (int ti = 0; ti < 2; ++ti) {
    const int t = t2[ti];
    if (t >= 0) {
      const int  rp   = 16 * t + a;
      const bool vld  = (rp < H4);
      const int  gate = rp & 3;
      const int  wrow = gate * H + (rp >> 2);
      const float sc  = (gate == 2) ? SCGP : SCI;
#pragma unroll
      for (int sp = 0; sp < 2; ++sp)
#pragma unroll
        for (int j = 0; j < 8; ++j) {
          const int k = 32 * sp + 16 * (j >> 2) + 4 * q + (j & 3);
          float val = 0.f;
          if (vld) {
            if (k < H)           val = SW[wrow * H + k];
            else if (k == H + 2) val = bih2[wrow] + bhh2[wrow];
          }
          wA2[ti][sp][j] = (_Float16)(val * sc);
        }
    }
  }
  __syncthreads();
  for (int i = tid; i < H4 * H; i += BLK) SW[i] = Whh2[i];
  __syncthreads();
#pragma unroll
  for (int ti = 0; ti < 2; ++ti) {
    const int t = t2[ti];
    if (t >= 0) {
      const int  rp   = 16 * t + a;
      const bool vld  = (rp < H4);
      const int  gate = rp & 3;
      const int  wrow = gate * H + (rp >> 2);
      const float sc  = (gate == 2) ? SCGP : SCI;
#pragma unroll
      for (int sp = 2; sp < 4; ++sp)
#pragma unroll
        for (int j = 0; j < 8; ++j) {
          const int kp = 32 * (sp - 2) + 16 * (j >> 2) + 4 * q + (j & 3);
          float val = (vld && kp < H) ? SW[wrow * H + kp] * sc : 0.f;
          wA2[ti][sp][j] = (_Float16)val;
        }
    }
  }
  if (isSpec) {
#pragma unroll
    for (int sp = 0; sp < 2; ++sp)
#pragma unroll
      for (int j = 0; j < 8; ++j) {
        const int kp = 32 * sp + 16 * (j >> 2) + 4 * q + (j & 3);
        float val = 0.f;
        if (a == 0) {
          if (kp < H)           val = Wlin[kp];
          else if (kp == H + 2) val = blin[0];
        }
        hA[sp][j] = (_Float16)val;
      }
  }

  // ---------------- init planes + x chunk 0 ----------------
  __syncthreads();
  for (int i = tid; i < 4096; i += BLK) PL[i] = 0;
  {  // preload x chunk 0 (steps 0..31): 512 threads x one float2
    const int st = tid >> 4, bi = tid & 15;
    XB[0][st][bi] = *(const float2*)(x + ((size_t)st * Bsz + b0 + bi) * 2);
  }
  __syncthreads();
  if (tid < 16) {
#pragma unroll
    for (int buf = 0; buf < 2; ++buf) {
      PL[(buf * 4 + 1) * 512 + (tid + 16) * 8 + 5] = 0x3C00;  // L1 const-1 (fp16 1.0)
      PL[(buf * 4 + 3) * 512 + (tid + 16) * 8 + 5] = 0x3C00;  // L2 const-1
    }
  }
  __syncthreads();
  if (isSpec && lane < 32) {  // inject x(0) into plane buf0
    const int bb = lane & 15, f = lane >> 4;
    const float xv = ((const float*)&XB[0][0][bb])[f];
    const int idx = 512 + ((f == 0) ? bb * 8 + 7 : (bb + 16) * 8 + 4);
    *(_Float16*)&PL[idx] = (_Float16)xv;
  }
  __syncthreads();

  // precomputed plane-write slots (lane owns u = 4*tile+q, batch = a)
  int  widx1[2] = {0, 0}, widx2[2] = {0, 0};
  bool uval1[2] = {false, false}, uval2[2] = {false, false};
#pragma unroll
  for (int ti = 0; ti < 2; ++ti) {
    if (t1[ti] >= 0) {
      const int u = 4 * t1[ti] + q;
      if (u < H) {
        uval1[ti] = true;
        const int spl = u >> 5, kl = u & 31;
        widx1[ti] = spl * 512 + (a + 16 * ((kl >> 2) & 3)) * 8 + ((kl & 3) + 4 * (kl >> 4));
      }
    }
    if (t2[ti] >= 0) {
      const int u = 4 * t2[ti] + q;
      if (u < H) {
        uval2[ti] = true;
        const int spl = u >> 5, kl = u & 31;
        widx2[ti] = 1024 + spl * 512 + (a + 16 * ((kl >> 2) & 3)) * 8 + ((kl & 3) + 4 * (kl >> 4));
      }
    }
  }

  float c1[2] = {0.f, 0.f}, c2[2] = {0.f, 0.f};
  float4 xcrA = {0,0,0,0}, xcrB = {0,0,0,0}, xcrC = {0,0,0,0}, xcrD = {0,0,0,0};
  float4* XB4 = (float4*)&XB[0][0][0];   // [2][256] float4 view

  for (int s = 0; s < T + 3; ++s) {
    const int pb   = (s & 1) * 2048;
    const int nbuf = 2048 - pb;

    // B-fragment reads: ONCE per wave, reused by all owned tiles
    f16x8 bh0 = *(const f16x8*)&PL[pb + lane * 8];
    f16x8 bh1 = *(const f16x8*)&PL[pb + 512 + lane * 8];
    f16x8 bh2 = *(const f16x8*)&PL[pb + 1024 + lane * 8];
    f16x8 bh3 = *(const f16x8*)&PL[pb + 1536 + lane * 8];

    // chores (spec wave): x chunk load / XB write / out flush
    if (isSpec) {
      const int ph = s & 31;
      if (ph == 0) {
        if (s + 32 < T) {   // load steps s+32 .. s+63 (4KB, 4 float4/lane)
          const size_t base = ((size_t)(s + 32) * Bsz + b0) * 2;
          const int f0 = lane, f1 = lane + 64, f2 = lane + 128, f3 = lane + 192;
          xcrA = *(const float4*)(x + base + (size_t)(f0 >> 3) * Bsz * 2 + (f0 & 7) * 4);
          xcrB = *(const float4*)(x + base + (size_t)(f1 >> 3) * Bsz * 2 + (f1 & 7) * 4);
          xcrC = *(const float4*)(x + base + (size_t)(f2 >> 3) * Bsz * 2 + (f2 & 7) * 4);
          xcrD = *(const float4*)(x + base + (size_t)(f3 >> 3) * Bsz * 2 + (f3 & 7) * 4);
        }
      } else if (ph == 1) {
        if (s + 31 < T) {
          const int buf = ((s >> 5) + 1) & 1;
          XB4[buf * 256 + lane]       = xcrA;
          XB4[buf * 256 + lane + 64]  = xcrB;
          XB4[buf * 256 + lane + 128] = xcrC;
          XB4[buf * 256 + lane + 192] = xcrD;
        }
      } else if (ph == 2 && s >= 34) {
        const int f = (s - 34) >> 5;
#pragma unroll
        for (int k = 0; k < 2; ++k) {
          const int idx = lane + 64 * k;
          const int r = idx >> 3, c4 = (idx & 7) * 4;
          const float4 v = *(const float4*)&OB[f & 1][r][c4];
          *(float4*)(out + (size_t)(b0 + r) * T + f * 32 + c4) = v;
        }
      }
    }

    // MFMA (tiles share the wave's B-fragments)
    f32x4 d1[2], d2[2];
#pragma unroll
    for (int ti = 0; ti < 2; ++ti) {
      if (t1[ti] >= 0) {
        f32x4 acc = {0.f, 0.f, 0.f, 0.f};
        acc = __builtin_amdgcn_mfma_f32_16x16x32_f16(wA1[ti][0], bh0, acc, 0, 0, 0);
        acc = __builtin_amdgcn_mfma_f32_16x16x32_f16(wA1[ti][1], bh1, acc, 0, 0, 0);
        d1[ti] = acc;
      }
      if (t2[ti] >= 0) {
        f32x4 acc = {0.f, 0.f, 0.f, 0.f};
        acc = __builtin_amdgcn_mfma_f32_16x16x32_f16(wA2[ti][0], bh0, acc, 0, 0, 0);
        acc = __builtin_amdgcn_mfma_f32_16x16x32_f16(wA2[ti][1], bh1, acc, 0, 0, 0);
        acc = __builtin_amdgcn_mfma_f32_16x16x32_f16(wA2[ti][2], bh2, acc, 0, 0, 0);
        acc = __builtin_amdgcn_mfma_f32_16x16x32_f16(wA2[ti][3], bh3, acc, 0, 0, 0);
        d2[ti] = acc;
      }
    }

    // activations + h-plane writes
    if (s < T) {
#pragma unroll
      for (int ti = 0; ti < 2; ++ti)
        if (t1[ti] >= 0) {
          const float h1 = lstm_act(d1[ti][0], d1[ti][1], d1[ti][2], d1[ti][3], c1[ti]);
          if (uval1[ti]) *(_Float16*)&PL[nbuf + widx1[ti]] = (_Float16)h1;
        }
    }
    if (s >= 1 && s <= T) {
#pragma unroll
      for (int ti = 0; ti < 2; ++ti)
        if (t2[ti] >= 0) {
          const float h2 = lstm_act(d2[ti][0], d2[ti][1], d2[ti][2], d2[ti][3], c2[ti]);
          if (uval2[ti]) *(_Float16*)&PL[nbuf + widx2[ti]] = (_Float16)h2;
        }
    }

    // head: out(s-2) -> OB ; x(s+1) injection into next buffer
    if (isSpec) {
      f32x4 dh = {0.f, 0.f, 0.f, 0.f};
      dh = __builtin_amdgcn_mfma_f32_16x16x32_f16(hA[0], bh2, dh, 0, 0, 0);
      dh = __builtin_amdgcn_mfma_f32_16x16x32_f16(hA[1], bh3, dh, 0, 0, 0);
      if (s >= 2 && s - 2 < T && lane < 16)
        OB[((s - 2) >> 5) & 1][lane][(s - 2) & 31] = dh[0];
      if (lane < 32 && s + 1 < T) {
        const int bb = lane & 15, f = lane >> 4;
        const int st = (s + 1) & 31, cb = ((s + 1) >> 5) & 1;
        const float xv = ((const float*)&XB[cb][st][bb])[f];
        const int idx = nbuf + 512 + ((f == 0) ? bb * 8 + 7 : (bb + 16) * 8 + 4);
        *(_Float16*)&PL[idx] = (_Float16)xv;
      }
    }
    BAR();
  }
}

extern "C" void kernel_launch(void* const* d_in, const int* in_sizes, int n_in,
                              void* d_out, int out_size, void* d_ws, size_t ws_size,
                              hipStream_t stream) {
  (void)in_sizes; (void)n_in; (void)d_ws; (void)ws_size; (void)out_size;
  const float* x    = (const float*)d_in[0];
  const float* Wih1 = (const float*)d_in[1];
  const float* Whh1 = (const float*)d_in[2];
  const float* bih1 = (const float*)d_in[3];
  const float* bhh1 = (const float*)d_in[4];
  const float* Wih2 = (const float*)d_in[5];
  const float* Whh2 = (const float*)d_in[6];
  const float* bih2 = (const float*)d_in[7];
  const float* bhh2 = (const float*)d_in[8];
  const float* Wlin = (const float*)d_in[9];
  const float* blin = (const float*)d_in[10];
  float* out = (float*)d_out;

  hipLaunchKernelGGL(lstm2_v7, dim3(GRID), dim3(BLK), 0, stream,
                     x, Wih1, Whh1, bih1, bhh1, Wih2, Whh2, bih2, bhh2,
                     Wlin, blin, out);
}

// Round 8
// 1313.470 us; speedup vs baseline: 1.5318x; 1.2084x over previous
//
#include <hip/hip_runtime.h>

namespace {
constexpr int T    = 2048;
constexpr int Bsz  = 4096;
constexpr int H    = 51;     // hidden units
constexpr int H4   = 204;    // 4*H gate rows
constexpr int NB   = 16;     // batches per block = MFMA free dim
constexpr int BLK  = 1024;   // 16 waves, 4 per SIMD
constexpr int GRID = Bsz / NB;  // 256 blocks = 1/CU
constexpr float SCI  = -1.44269504f;  // -log2(e): i,f,o gates
constexpr float SCGP =  2.88539008f;  // +2*log2(e): g gate (e^{2g}, |g|<~10 bounded)
constexpr float SC2  = -2.88539008f;  // -2*log2(e): tanh(c) abs-form (c unbounded)
}

typedef float    f32x4 __attribute__((ext_vector_type(4)));
typedef _Float16 f16x8 __attribute__((ext_vector_type(8)));
typedef unsigned short u16;

__device__ __forceinline__ float RCP(float x)  { return __builtin_amdgcn_rcpf(x); }
__device__ __forceinline__ float EXP2(float x) { return __builtin_amdgcn_exp2f(x); }

// Gi=-log2e*i, Gf=-log2e*f, Gg=+2log2e*g, Go=-log2e*o (pre-scaled into weights)
// c' = [c*pig + (eg-1)*pf] / (pig*pf) ;  h = copysign(1-ec,c') / ((1+ec)*po)
__device__ __forceinline__ float lstm_act(float Gi, float Gf, float Gg, float Go, float& c) {
  float ei = EXP2(Gi), ef = EXP2(Gf), eo = EXP2(Go), eg = EXP2(Gg);
  float pi = 1.f + ei, pf = 1.f + ef, pg = 1.f + eg, po = 1.f + eo;
  float pig = pi * pg;
  float num = fmaf(c, pig, (eg - 1.f) * pf);
  c = num * RCP(pig * pf);
  float ec = EXP2(SC2 * fabsf(c));
  float tc = copysignf(1.f - ec, c);
  return tc * RCP((1.f + ec) * po);
}

// main-loop barrier: LDS-visibility only; do NOT drain vmcnt (chore waves'
// global loads/stores stay in flight across barriers)
#define BAR() asm volatile("s_waitcnt lgkmcnt(0)\n\ts_barrier" ::: "memory")

// Fragment k-map (validated r2-r7): lane = free(0..15)+16*q ; elem j: k = 32*sp+16*(j>>2)+4*q+(j&3)
// h-plane slot (b,k): sp=k>>5, kl=k&31, row=b+16*((kl>>2)&3), j=(kl&3)+4*(kl>>4)
// PL shorts: [buf(2)][layer(2)][sp(2)][row(64)][j(8)] = 4096 shorts = 8KB
// L1 k-slots: k<51 h1 | 51 x0 | 52 x1 | 53 const1 ; L2 (k-64): <51 h2 | 53 const1

__global__ __launch_bounds__(BLK, 4) void lstm2_v8(
    const float* __restrict__ x,
    const float* __restrict__ Wih1, const float* __restrict__ Whh1,
    const float* __restrict__ bih1, const float* __restrict__ bhh1,
    const float* __restrict__ Wih2, const float* __restrict__ Whh2,
    const float* __restrict__ bih2, const float* __restrict__ bhh2,
    const float* __restrict__ Wlin, const float* __restrict__ blin,
    float* __restrict__ out) {
  __shared__ __align__(16) float  SW[H4 * H];      // 41.6 KB staging (init only)
  __shared__ __align__(16) u16    PL[4096];        // 8 KB h-plane ping-pong
  __shared__ __align__(16) float2 XB[2][32][16];   // 8 KB x chunk double-buffer
  __shared__ __align__(16) float  OB[2][16][36];   // 4.6 KB out chunk

  const int tid  = threadIdx.x;
  const int lane = tid & 63;
  const int wid  = tid >> 6;
  const int a    = lane & 15;
  const int q    = lane >> 4;
  const int b0   = blockIdx.x * NB;
  const int lt   = tid - 768;       // chore lane (waves 12-15)

  // tile-pair map: <=2 same-layer tiles per wave; 16 waves; SIMD act balance
  // S0{w0,4,8,12}=7, S1{w1,5,9,13}=7, S2{w2,6,10,14}=6+head, S3{w3,7,11,15}=6+xinj
  int tA = -1, tB = -1; bool isL1 = false;
  switch (wid) {
    case 0:  isL1 = true;  tA = 0;  tB = 1;  break;
    case 1:  isL1 = true;  tA = 4;  tB = 5;  break;
    case 2:  isL1 = true;  tA = 8;  tB = 9;  break;
    case 3:  isL1 = true;  tA = 10; tB = 11; break;
    case 4:  isL1 = true;  tA = 2;  tB = 3;  break;
    case 5:  isL1 = true;  tA = 6;  tB = 7;  break;
    case 6:  tA = 6;  tB = 7;  break;   // L2
    case 7:  isL1 = true;  tA = 12; break;
    case 8:  tA = 0;  tB = 1;  break;   // L2
    case 9:  tA = 3;  tB = 4;  break;   // L2
    case 10: tA = 8;  tB = 9;  break;   // L2
    case 11: tA = 10; tB = 11; break;   // L2
    case 12: tA = 2;  break;            // L2
    case 13: tA = 5;  break;            // L2
    case 14: break;                     // head
    case 15: tA = 12; break;            // L2 + xinj
  }
  const bool isHead = (wid == 14);
  const bool isXinj = (wid == 15);
  const bool isL2   = (!isL1) && (tA >= 0);

  // ---------------- init: weight A-fragments (pre-scaled single fp16) ----------------
  f16x8 wA[2][4];   // [tile][sp]; L1 uses sp0-1, L2 sp0-3
  f16x8 hA[2];      // head: Wlin + blin

  for (int i = tid; i < H4 * H; i += BLK) SW[i] = Whh1[i];
  __syncthreads();
  if (isL1) {
#pragma unroll
    for (int ti = 0; ti < 2; ++ti) {
      const int t = ti ? tB : tA;
      if (t >= 0) {
        const int  rp   = 16 * t + a;
        const bool vld  = (rp < H4);
        const int  gate = rp & 3;
        const int  wrow = gate * H + (rp >> 2);
        const float sc  = (gate == 2) ? SCGP : SCI;
#pragma unroll
        for (int sp = 0; sp < 2; ++sp)
#pragma unroll
          for (int j = 0; j < 8; ++j) {
            const int k = 32 * sp + 16 * (j >> 2) + 4 * q + (j & 3);
            float val = 0.f;
            if (vld) {
              if (k < H)           val = SW[wrow * H + k];
              else if (k == H)     val = Wih1[wrow * 2 + 0];
              else if (k == H + 1) val = Wih1[wrow * 2 + 1];
              else if (k == H + 2) val = bih1[wrow] + bhh1[wrow];
            }
            wA[ti][sp][j] = (_Float16)(val * sc);
          }
      }
    }
  }
  __syncthreads();
  for (int i = tid; i < H4 * H; i += BLK) SW[i] = Wih2[i];
  __syncthreads();
  if (isL2) {
#pragma unroll
    for (int ti = 0; ti < 2; ++ti) {
      const int t = ti ? tB : tA;
      if (t >= 0) {
        const int  rp   = 16 * t + a;
        const bool vld  = (rp < H4);
        const int  gate = rp & 3;
        const int  wrow = gate * H + (rp >> 2);
        const float sc  = (gate == 2) ? SCGP : SCI;
#pragma unroll
        for (int sp = 0; sp < 2; ++sp)
#pragma unroll
          for (int j = 0; j < 8; ++j) {
            const int k = 32 * sp + 16 * (j >> 2) + 4 * q + (j & 3);
            float val = 0.f;
            if (vld) {
              if (k < H)           val = SW[wrow * H + k];
              else if (k == H + 2) val = bih2[wrow] + bhh2[wrow];
            }
            wA[ti][sp][j] = (_Float16)(val * sc);
          }
      }
    }
  }
  __syncthreads();
  for (int i = tid; i < H4 * H; i += BLK) SW[i] = Whh2[i];
  __syncthreads();
  if (isL2) {
#pragma unroll
    for (int ti = 0; ti < 2; ++ti) {
      const int t = ti ? tB : tA;
      if (t >= 0) {
        const int  rp   = 16 * t + a;
        const bool vld  = (rp < H4);
        const int  gate = rp & 3;
        const int  wrow = gate * H + (rp >> 2);
        const float sc  = (gate == 2) ? SCGP : SCI;
#pragma unroll
        for (int sp = 2; sp < 4; ++sp)
#pragma unroll
          for (int j = 0; j < 8; ++j) {
            const int kp = 32 * (sp - 2) + 16 * (j >> 2) + 4 * q + (j & 3);
            float val = (vld && kp < H) ? SW[wrow * H + kp] * sc : 0.f;
            wA[ti][sp][j] = (_Float16)val;
          }
      }
    }
  }
  if (isHead) {
#pragma unroll
    for (int sp = 0; sp < 2; ++sp)
#pragma unroll
      for (int j = 0; j < 8; ++j) {
        const int kp = 32 * sp + 16 * (j >> 2) + 4 * q + (j & 3);
        float val = 0.f;
        if (a == 0) {
          if (kp < H)           val = Wlin[kp];
          else if (kp == H + 2) val = blin[0];
        }
        hA[sp][j] = (_Float16)val;
      }
  }

  // ---------------- init planes + x chunk 0 ----------------
  __syncthreads();
  for (int i = tid; i < 4096; i += BLK) PL[i] = 0;
  if (lt >= 0) {  // preload x chunk 0 (steps 0..31): 256 lanes x float4
    const int st = lt >> 3, bc = (lt & 7) * 2;
    *(float4*)&XB[0][st][bc] = *(const float4*)(x + ((size_t)st * Bsz + b0 + bc) * 2);
  }
  __syncthreads();
  if (tid < 16) {
#pragma unroll
    for (int buf = 0; buf < 2; ++buf) {
      PL[(buf * 4 + 1) * 512 + (tid + 16) * 8 + 5] = 0x3C00;  // L1 const-1 (fp16 1.0)
      PL[(buf * 4 + 3) * 512 + (tid + 16) * 8 + 5] = 0x3C00;  // L2 const-1
    }
  }
  __syncthreads();
  if (isXinj && lane < 32) {  // inject x(0) into plane buf0
    const int bb = lane & 15, f = lane >> 4;
    const float xv = ((const float*)&XB[0][0][bb])[f];
    const int idx = 512 + ((f == 0) ? bb * 8 + 7 : (bb + 16) * 8 + 4);
    *(_Float16*)&PL[idx] = (_Float16)xv;
  }
  __syncthreads();

  // precomputed plane-write slots (lane owns u = 4*tile+q, batch = a)
  int  widx[2] = {0, 0};
  bool uval[2] = {false, false};
#pragma unroll
  for (int ti = 0; ti < 2; ++ti) {
    const int t = ti ? tB : tA;
    if (t >= 0) {
      const int u = 4 * t + q;
      if (u < H) {
        uval[ti] = true;
        const int spl = u >> 5, kl = u & 31;
        widx[ti] = (isL2 ? 1024 : 0) + spl * 512 +
                   (a + 16 * ((kl >> 2) & 3)) * 8 + ((kl & 3) + 4 * (kl >> 4));
      }
    }
  }

  float cc[2] = {0.f, 0.f};
  float4 xcr = {0.f, 0.f, 0.f, 0.f};
  const int rb = lane * 8;

#define DO_SLOT(S, PB, NBF)                                                        \
  {                                                                                \
    const int s = (S);                                                             \
    /* B-fragment reads (per-wave minimal set) */                                  \
    f16x8 bh0, bh1, bh2, bh3;                                                      \
    if (isL1 || isL2) {                                                            \
      bh0 = *(const f16x8*)&PL[(PB) + rb];                                         \
      bh1 = *(const f16x8*)&PL[(PB) + 512 + rb];                                   \
    }                                                                              \
    if (isL2 || isHead) {                                                          \
      bh2 = *(const f16x8*)&PL[(PB) + 1024 + rb];                                  \
      bh3 = *(const f16x8*)&PL[(PB) + 1536 + rb];                                  \
    }                                                                              \
    /* chores (waves 12-15): x chunk load / XB write / out flush */                \
    if (lt >= 0) {                                                                 \
      const int ph = s & 31;                                                       \
      if (ph == 0) {                                                               \
        if (s + 32 < T) {                                                          \
          const int st = lt >> 3, bc = (lt & 7) * 2;                               \
          xcr = *(const float4*)(x + ((size_t)(s + 32 + st) * Bsz + b0 + bc) * 2); \
        }                                                                          \
      } else if (ph == 1) {                                                        \
        if (s + 31 < T) {                                                          \
          const int buf = ((s >> 5) + 1) & 1;                                      \
          const int st = lt >> 3, bc = (lt & 7) * 2;                               \
          *(float4*)&XB[buf][st][bc] = xcr;                                        \
        }                                                                          \
      } else if (ph == 2 && s >= 34) {                                             \
        const int f = (s - 34) >> 5;                                               \
        const int row = lt >> 4, c0 = (lt & 15) * 2;                               \
        const float2 v = *(const float2*)&OB[f & 1][row][c0];                      \
        *(float2*)(out + (size_t)(b0 + row) * T + f * 32 + c0) = v;                \
      }                                                                            \
    }                                                                              \
    /* MFMA */                                                                     \
    f32x4 dA, dB;                                                                  \
    if (isL1) {                                                                    \
      f32x4 acc = {0.f, 0.f, 0.f, 0.f};                                            \
      acc = __builtin_amdgcn_mfma_f32_16x16x32_f16(wA[0][0], bh0, acc, 0, 0, 0);   \
      acc = __builtin_amdgcn_mfma_f32_16x16x32_f16(wA[0][1], bh1, acc, 0, 0, 0);   \
      dA = acc;                                                                    \
      if (tB >= 0) {                                                               \
        f32x4 ac2 = {0.f, 0.f, 0.f, 0.f};                                          \
        ac2 = __builtin_amdgcn_mfma_f32_16x16x32_f16(wA[1][0], bh0, ac2, 0, 0, 0); \
        ac2 = __builtin_amdgcn_mfma_f32_16x16x32_f16(wA[1][1], bh1, ac2, 0, 0, 0); \
        dB = ac2;                                                                  \
      }                                                                            \
    } else if (isL2) {                                                             \
      f32x4 acc = {0.f, 0.f, 0.f, 0.f};                                            \
      acc = __builtin_amdgcn_mfma_f32_16x16x32_f16(wA[0][2], bh2, acc, 0, 0, 0);   \
      acc = __builtin_amdgcn_mfma_f32_16x16x32_f16(wA[0][3], bh3, acc, 0, 0, 0);   \
      acc = __builtin_amdgcn_mfma_f32_16x16x32_f16(wA[0][0], bh0, acc, 0, 0, 0);   \
      acc = __builtin_amdgcn_mfma_f32_16x16x32_f16(wA[0][1], bh1, acc, 0, 0, 0);   \
      dA = acc;                                                                    \
      if (tB >= 0) {                                                               \
        f32x4 ac2 = {0.f, 0.f, 0.f, 0.f};                                          \
        ac2 = __builtin_amdgcn_mfma_f32_16x16x32_f16(wA[1][2], bh2, ac2, 0, 0, 0); \
        ac2 = __builtin_amdgcn_mfma_f32_16x16x32_f16(wA[1][3], bh3, ac2, 0, 0, 0); \
        ac2 = __builtin_amdgcn_mfma_f32_16x16x32_f16(wA[1][0], bh0, ac2, 0, 0, 0); \
        ac2 = __builtin_amdgcn_mfma_f32_16x16x32_f16(wA[1][1], bh1, ac2, 0, 0, 0); \
        dB = ac2;                                                                  \
      }                                                                            \
    }                                                                              \
    /* activations + h-plane writes */                                             \
    const bool on = isL1 ? (s < T) : (s >= 1 && s <= T);                           \
    if ((isL1 || isL2) && on) {                                                    \
      const float hA_ = lstm_act(dA[0], dA[1], dA[2], dA[3], cc[0]);               \
      if (uval[0]) *(_Float16*)&PL[(NBF) + widx[0]] = (_Float16)hA_;               \
      if (tB >= 0) {                                                               \
        const float hB_ = lstm_act(dB[0], dB[1], dB[2], dB[3], cc[1]);             \
        if (uval[1]) *(_Float16*)&PL[(NBF) + widx[1]] = (_Float16)hB_;             \
      }                                                                            \
    }                                                                              \
    /* head: out(s-2) -> OB */                                                     \
    if (isHead) {                                                                  \
      f32x4 dh = {0.f, 0.f, 0.f, 0.f};                                             \
      dh = __builtin_amdgcn_mfma_f32_16x16x32_f16(hA[0], bh2, dh, 0, 0, 0);        \
      dh = __builtin_amdgcn_mfma_f32_16x16x32_f16(hA[1], bh3, dh, 0, 0, 0);        \
      if (s >= 2 && s - 2 < T && lane < 16)                                        \
        OB[((s - 2) >> 5) & 1][lane][(s - 2) & 31] = dh[0];                        \
    }                                                                              \
    /* x(s+1) injection into next buffer */                                        \
    if (isXinj && lane < 32 && s + 1 < T) {                                        \
      const int bb = lane & 15, f = lane >> 4;                                     \
      const int st = (s + 1) & 31, cb = ((s + 1) >> 5) & 1;                        \
      const float xv = ((const float*)&XB[cb][st][bb])[f];                         \
      const int idx = (NBF) + 512 + ((f == 0) ? bb * 8 + 7 : (bb + 16) * 8 + 4);   \
      *(_Float16*)&PL[idx] = (_Float16)xv;                                         \
    }                                                                              \
    BAR();                                                                         \
  }

  for (int s0 = 0; s0 < T + 4; s0 += 2) {
    DO_SLOT(s0, 0, 2048)
    DO_SLOT(s0 + 1, 2048, 0)
  }
#undef DO_SLOT
}

extern "C" void kernel_launch(void* const* d_in, const int* in_sizes, int n_in,
                              void* d_out, int out_size, void* d_ws, size_t ws_size,
                              hipStream_t stream) {
  (void)in_sizes; (void)n_in; (void)d_ws; (void)ws_size; (void)out_size;
  const float* x    = (const float*)d_in[0];
  const float* Wih1 = (const float*)d_in[1];
  const float* Whh1 = (const float*)d_in[2];
  const float* bih1 = (const float*)d_in[3];
  const float* bhh1 = (const float*)d_in[4];
  const float* Wih2 = (const float*)d_in[5];
  const float* Whh2 = (const float*)d_in[6];
  const float* bih2 = (const float*)d_in[7];
  const float* bhh2 = (const float*)d_in[8];
  const float* Wlin = (const float*)d_in[9];
  const float* blin = (const float*)d_in[10];
  float* out = (float*)d_out;

  hipLaunchKernelGGL(lstm2_v8, dim3(GRID), dim3(BLK), 0, stream,
                     x, Wih1, Whh1, bih1, bhh1, Wih2, Whh2, bih2, bhh2,
                     Wlin, blin, out);
}